// Round 7
// baseline (495.208 us; speedup 1.0000x reference)
//
#include <hip/hip_runtime.h>

#define NEGF -1000000000.0f
#define LOG2E 1.4426950408889634f
#define LN2 0.6931471805599453f

constexpr int Bn = 64;
constexpr int Tn = 1000;
constexpr int Un = 250;
constexpr int NZROW = Bn * Tn / 16;  // 4000 zrow blocks, 16 rows each

// gfx950-native base-2 transcendentals: v_exp_f32 is 2^x, v_log_f32 is log2(x)
__device__ __forceinline__ float exp2fast(float x) { return __builtin_amdgcn_exp2f(x); }
__device__ __forceinline__ float log2fast(float x) { return __builtin_amdgcn_logf(x); }

// ---------------------------------------------------------------------------
// DPP cross-lane ops (gfx9-lineage controls, retained on CDNA4).
//   wave_shr:1 (0x138) + bound_ctrl=1: lane i <- lane i-1, lane 0 <- 0.
//   Reductions: row_shr 1/2/4/8 + row_bcast:15/31, result in lane 63.
// ---------------------------------------------------------------------------
template <int CTRL>
__device__ __forceinline__ float dppmov(float x) {
    return __int_as_float(__builtin_amdgcn_update_dpp(
        0, __float_as_int(x), CTRL, 0xf, 0xf, true));
}
__device__ __forceinline__ float dpp_wave_shr1(float x) { return dppmov<0x138>(x); }

__device__ __forceinline__ float wave_red_max(float x) {  // = max(max_x, 0)
    x = fmaxf(x, dppmov<0x111>(x));
    x = fmaxf(x, dppmov<0x112>(x));
    x = fmaxf(x, dppmov<0x114>(x));
    x = fmaxf(x, dppmov<0x118>(x));
    x = fmaxf(x, dppmov<0x142>(x));
    x = fmaxf(x, dppmov<0x143>(x));
    return __int_as_float(__builtin_amdgcn_readlane(__float_as_int(x), 63));
}
__device__ __forceinline__ float wave_red_sum(float x) {
    x += dppmov<0x111>(x);
    x += dppmov<0x112>(x);
    x += dppmov<0x114>(x);
    x += dppmov<0x118>(x);
    x += dppmov<0x142>(x);
    x += dppmov<0x143>(x);
    return __int_as_float(__builtin_amdgcn_readlane(__float_as_int(x), 63));
}

typedef float v2f __attribute__((ext_vector_type(2)));

// ---------------------------------------------------------------------------
// CTC macros: PROVEN round-6 machinery, verbatim. q = exp2(fma(..)) computed
// 8 steps ahead of consumption; 32 loads in flight; per-slot register-tied
// vmcnt(30) waits; renorm every 8 steps.
// ---------------------------------------------------------------------------
#define CTC_REFILL(J, T)                                                      \
    {                                                                         \
        int tl_ = (T) <= last ? (T) : last;                                   \
        const char* rowp_ = pbase + (size_t)tl_ * 1000;                       \
        asm volatile("global_load_dwordx2 %0, %1, %2"                         \
                     : "=v"(lo[J]) : "v"(voff_lo), "s"(rowp_));               \
        asm volatile("global_load_dwordx2 %0, %1, %2"                         \
                     : "=v"(hi[J]) : "v"(voff_hi), "s"(rowp_));               \
    }

#define QGEN(Q, S, WCNT)                                                      \
    {                                                                         \
        asm volatile("s_waitcnt vmcnt(" #WCNT ")"                             \
                     : "+v"(lo[S]), "+v"(hi[S]));                             \
        qa[Q] = exp2fast(__builtin_fmaf(lo[S].x, LOG2E, bias0));              \
        qb[Q] = exp2fast(__builtin_fmaf(lo[S].y, LOG2E, bias1));              \
        qc[Q] = exp2fast(__builtin_fmaf(hi[S].x, LOG2E, bias2));              \
        qd[Q] = exp2fast(__builtin_fmaf(hi[S].y, LOG2E, bias3));              \
    }

#define STEP_Q(Q)                                                             \
    {                                                                         \
        float q0 = qa[Q], q1 = qb[Q], q2 = qc[Q], q3 = qd[Q];                 \
        float p7 = dpp_wave_shr1(a7); /* old a7 of lane-1; lane0 -> 0 */      \
        float s65 = a6 + a5, s43 = a4 + a3, s21 = a2 + a1, s0p = a0 + p7;     \
        a7 = (a7 + s65) * q3;  a6 = s65 * QB;                                 \
        a5 = (a5 + s43) * q2;  a4 = s43 * QB;                                 \
        a3 = (a3 + s21) * q1;  a2 = s21 * QB;                                 \
        a1 = (a1 + s0p) * q0;  a0 = s0p * QB;                                 \
    }

#define RENORM()                                                              \
    {                                                                         \
        float mx = fmaxf(fmaxf(fmaxf(a0, a1), fmaxf(a2, a3)),                 \
                         fmaxf(fmaxf(a4, a5), fmaxf(a6, a7)));                \
        mx = wave_red_max(mx); /* alphas >= 0, mx > 0 always */               \
        int e_ = (int)((__float_as_uint(mx) >> 23) & 255) - 127;              \
        float scale_ = __uint_as_float((unsigned)(127 - e_) << 23);           \
        a0 *= scale_; a1 *= scale_; a2 *= scale_; a3 *= scale_;               \
        a4 *= scale_; a5 *= scale_; a6 *= scale_; a7 *= scale_;               \
        Esum += (float)e_;                                                    \
    }

// ---------------------------------------------------------------------------
// FUSED kernel. Blocks 0..63: CTC recursion for batch b (wave 0 only; the
// recursion is independent of Z2 until its epilogue, which spin-waits on the
// zrow completion counter with device-scope acquire loads). Blocks 64..4063:
// proven zrow body (4 waves x 4 rows), then threadfence + barrier + counter
// increment. zrow blocks never wait on anything -> deadlock-free under any
// dispatch order (worst case degrades to today's serialization).
// ---------------------------------------------------------------------------
__global__ void __launch_bounds__(256) fused_kernel(const float* __restrict__ attn,
                                                    const int* __restrict__ text_lens,
                                                    const int* __restrict__ mel_lens,
                                                    float* __restrict__ Z2,
                                                    unsigned int* __restrict__ done,
                                                    float* __restrict__ out) {
    if (blockIdx.x >= (unsigned)Bn) {
        // ---------------- zrow portion (PROVEN body, verbatim) ----------------
        int bz = blockIdx.x - Bn;              // 0..3999
        if (bz == 0 && threadIdx.x == 0) *out = 0.0f;
        int wid = threadIdx.x >> 6;
        int lane = threadIdx.x & 63;
        int row0 = (bz * 4 + wid) * 4;         // 4 consecutive rows per wave

        float v[4][4];
        int Ls[4];
#pragma unroll
        for (int r = 0; r < 4; ++r) {
            int row = row0 + r;
            Ls[r] = text_lens[row / Tn];
            const float* p = attn + (size_t)row * Un;
#pragma unroll
            for (int i = 0; i < 4; ++i) {
                int u = lane + 64 * i;
                v[r][i] = (u < Un) ? p[u] : 0.0f;  // in-bounds; mask vs L below
            }
        }
#pragma unroll
        for (int r = 0; r < 4; ++r) {
            int L = Ls[r];
            float m = (lane == 0) ? -LOG2E : NEGF;
#pragma unroll
            for (int i = 0; i < 4; ++i) {
                int u = lane + 64 * i;
                v[r][i] = (u < L) ? v[r][i] * LOG2E : NEGF;
                m = fmaxf(m, v[r][i]);
            }
            m = wave_red_max(m);               // wave-uniform; exact pow2 shift
            float s = (lane == 0) ? exp2fast(-LOG2E - m) : 0.0f;
#pragma unroll
            for (int i = 0; i < 4; ++i) s += exp2fast(v[r][i] - m);  // NEGF-m -> 0
            s = wave_red_sum(s);
            if (lane == 0) Z2[row0 + r] = m + log2fast(s);
        }
        // publish: each thread fences its own stores, barrier, then one flag
        __threadfence();
        __syncthreads();
        if (threadIdx.x == 0) atomicAdd(done, 1u);
        return;
    }

    // ------------------- ctc portion (PROVEN round-6 body) -------------------
    if (threadIdx.x >= 64) return;             // 1 wave per ctc block
    int b = blockIdx.x;
    int lane = threadIdx.x;
    int L = text_lens[b];
    int n_t = mel_lens[b];
    const char* pbase = (const char*)(attn + (size_t)b * Tn * Un);

    // per-lane safe byte offsets within a 1000B row (8B aligned, never OOB):
    // lane62 hi aliases lo (its cols 250/251 are always masked since L<=250),
    // lane63 reads col 0 (all its states masked).
    int voff_lo = lane * 16, voff_hi = lane * 16 + 8;
    if (lane == 62) { voff_lo = 992; voff_hi = 992; }
    if (lane == 63) { voff_lo = 0;   voff_hi = 0;   }
    int c0 = lane * 4;
    float bias0 = (c0 + 0 < L) ? 0.0f : -1000000.0f;
    float bias1 = (c0 + 1 < L) ? 0.0f : -1000000.0f;
    float bias2 = (c0 + 2 < L) ? 0.0f : -1000000.0f;
    float bias3 = (c0 + 3 < L) ? 0.0f : -1000000.0f;

    const float QB = 0.36787944117144233f;  // e^-1 (blank, unnormalized)
    float a0 = (lane == 0) ? 1.0f : 0.0f;
    float a1 = 0.0f, a2 = 0.0f, a3 = 0.0f, a4 = 0.0f, a5 = 0.0f, a6 = 0.0f, a7 = 0.0f;
    float Esum = 0.0f;  // accumulated renorm exponent, log2 units

    v2f lo[16], hi[16];
    float qa[8], qb[8], qc[8], qd[8];
    int last = n_t - 1;

    // prologue: slots 0..15 <- rows 0..15 (32 loads in flight)
#pragma unroll
    for (int j = 0; j < 16; ++j) CTC_REFILL(j, j);
    QGEN(0, 0, 30); QGEN(1, 1, 28); QGEN(2, 2, 26); QGEN(3, 3, 24);
    QGEN(4, 4, 22); QGEN(5, 5, 20); QGEN(6, 6, 18); QGEN(7, 7, 16);
#pragma unroll
    for (int j = 0; j < 8; ++j) CTC_REFILL(j, 16 + j);

    int full = n_t & ~15;
    int t = 0;
    for (; t < full; t += 16) {
        STEP_Q(0); QGEN(0, 8, 30);  CTC_REFILL(8,  t + 24);
        STEP_Q(1); QGEN(1, 9, 30);  CTC_REFILL(9,  t + 25);
        STEP_Q(2); QGEN(2, 10, 30); CTC_REFILL(10, t + 26);
        STEP_Q(3); QGEN(3, 11, 30); CTC_REFILL(11, t + 27);
        STEP_Q(4); QGEN(4, 12, 30); CTC_REFILL(12, t + 28);
        STEP_Q(5); QGEN(5, 13, 30); CTC_REFILL(13, t + 29);
        STEP_Q(6); QGEN(6, 14, 30); CTC_REFILL(14, t + 30);
        STEP_Q(7); QGEN(7, 15, 30); CTC_REFILL(15, t + 31);
        RENORM();
        STEP_Q(0); QGEN(0, 0, 30);  CTC_REFILL(0, t + 32);
        STEP_Q(1); QGEN(1, 1, 30);  CTC_REFILL(1, t + 33);
        STEP_Q(2); QGEN(2, 2, 30);  CTC_REFILL(2, t + 34);
        STEP_Q(3); QGEN(3, 3, 30);  CTC_REFILL(3, t + 35);
        STEP_Q(4); QGEN(4, 4, 30);  CTC_REFILL(4, t + 36);
        STEP_Q(5); QGEN(5, 5, 30);  CTC_REFILL(5, t + 37);
        STEP_Q(6); QGEN(6, 6, 30);  CTC_REFILL(6, t + 38);
        STEP_Q(7); QGEN(7, 7, 30);  CTC_REFILL(7, t + 39);
        RENORM();
    }
    // tail (<= 15 steps). q[0..7] hold rows full..full+7; slots 8..14 hold
    // rows full+8..full+14 (clamped).
    if (t + 0 < n_t) STEP_Q(0);
    if (t + 1 < n_t) STEP_Q(1);
    if (t + 2 < n_t) STEP_Q(2);
    if (t + 3 < n_t) STEP_Q(3);
    if (t + 4 < n_t) STEP_Q(4);
    if (t + 5 < n_t) STEP_Q(5);
    if (t + 6 < n_t) STEP_Q(6);
    if (t + 7 < n_t) STEP_Q(7);
    if (t + 8 < n_t)  { RENORM(); QGEN(0, 8, 0); STEP_Q(0); }  // cap run at 8
    if (t + 9 < n_t)  { QGEN(1, 9, 0);  STEP_Q(1); }
    if (t + 10 < n_t) { QGEN(2, 10, 0); STEP_Q(2); }
    if (t + 11 < n_t) { QGEN(3, 11, 0); STEP_Q(3); }
    if (t + 12 < n_t) { QGEN(4, 12, 0); STEP_Q(4); }
    if (t + 13 < n_t) { QGEN(5, 13, 0); STEP_Q(5); }
    if (t + 14 < n_t) { QGEN(6, 14, 0); STEP_Q(6); }
    asm volatile("s_waitcnt vmcnt(0)" ::: "memory");  // drain stale prefetches

    __shared__ float sal[512];
    sal[lane * 8 + 0] = a0;
    sal[lane * 8 + 1] = a1;
    sal[lane * 8 + 2] = a2;
    sal[lane * 8 + 3] = a3;
    sal[lane * 8 + 4] = a4;
    sal[lane * 8 + 5] = a5;
    sal[lane * 8 + 6] = a6;
    sal[lane * 8 + 7] = a7;
    // single wave: LDS write->read ordering needs only lgkmcnt (no barrier;
    // waves 1..3 exited so s_barrier would be unsafe here)
    asm volatile("s_waitcnt lgkmcnt(0)" ::: "memory");

    // wait for all zrow blocks (device-scope acquire) before reading Z2/out
    while (__hip_atomic_load(done, __ATOMIC_ACQUIRE, __HIP_MEMORY_SCOPE_AGENT)
           < (unsigned)NZROW) {
        __builtin_amdgcn_s_sleep(32);
    }

    // sum of log-softmax denominators over t < n_t (log2 units)
    float zs = 0.0f;
    for (int i = lane; i < n_t; i += 64) zs += Z2[b * Tn + i];
    zs = wave_red_sum(zs);

    if (lane == 0) {
        float ssum = sal[2 * L] + sal[2 * L - 1];
        float fin = (log2fast(ssum) + Esum - zs) * LN2;
        float loss = (ssum <= 0.0f) ? 0.0f : (-fin / (float)L);
        atomicAdd(out, loss * (1.0f / (float)Bn));
    }
}

extern "C" void kernel_launch(void* const* d_in, const int* in_sizes, int n_in,
                              void* d_out, int out_size, void* d_ws, size_t ws_size,
                              hipStream_t stream) {
    const float* attn = (const float*)d_in[0];
    const int* text_lens = (const int*)d_in[1];
    const int* mel_lens = (const int*)d_in[2];
    float* out = (float*)d_out;

    // workspace layout: [0,1024) done-counter (zeroed each launch, survives
    // re-poisoning); [1024, 1024 + 256KB) Z2.
    unsigned int* done = (unsigned int*)d_ws;
    float* Z2 = (float*)((char*)d_ws + 1024);

    hipMemsetAsync(d_ws, 0, 1024, stream);  // stream-ordered, graph-capturable
    fused_kernel<<<Bn + NZROW, 256, 0, stream>>>(attn, text_lens, mel_lens,
                                                 Z2, done, out);
}

// Round 8
// 161.149 us; speedup vs baseline: 3.0730x; 3.0730x over previous
//
#include <hip/hip_runtime.h>

#define NEGF -1000000000.0f
#define LOG2E 1.4426950408889634f
#define LN2 0.6931471805599453f

constexpr int Bn = 64;
constexpr int Tn = 1000;
constexpr int Un = 250;

// gfx950-native base-2 transcendentals: v_exp_f32 is 2^x, v_log_f32 is log2(x)
__device__ __forceinline__ float exp2fast(float x) { return __builtin_amdgcn_exp2f(x); }
__device__ __forceinline__ float log2fast(float x) { return __builtin_amdgcn_logf(x); }

// ---------------------------------------------------------------------------
// DPP cross-lane ops (gfx9-lineage controls, retained on CDNA4).
//   wave_shr:1 (0x138) + bound_ctrl=1: lane i <- lane i-1, lane 0 <- 0.
//   Reductions: row_shr 1/2/4/8 + row_bcast:15/31, result in lane 63.
// ---------------------------------------------------------------------------
template <int CTRL>
__device__ __forceinline__ float dppmov(float x) {
    return __int_as_float(__builtin_amdgcn_update_dpp(
        0, __float_as_int(x), CTRL, 0xf, 0xf, true));
}
__device__ __forceinline__ float dpp_wave_shr1(float x) { return dppmov<0x138>(x); }

__device__ __forceinline__ float wave_red_max(float x) {  // = max(max_x, 0)
    x = fmaxf(x, dppmov<0x111>(x));
    x = fmaxf(x, dppmov<0x112>(x));
    x = fmaxf(x, dppmov<0x114>(x));
    x = fmaxf(x, dppmov<0x118>(x));
    x = fmaxf(x, dppmov<0x142>(x));
    x = fmaxf(x, dppmov<0x143>(x));
    return __int_as_float(__builtin_amdgcn_readlane(__float_as_int(x), 63));
}
__device__ __forceinline__ float wave_red_sum(float x) {
    x += dppmov<0x111>(x);
    x += dppmov<0x112>(x);
    x += dppmov<0x114>(x);
    x += dppmov<0x118>(x);
    x += dppmov<0x142>(x);
    x += dppmov<0x143>(x);
    return __int_as_float(__builtin_amdgcn_readlane(__float_as_int(x), 63));
}

typedef float v2f __attribute__((ext_vector_type(2)));

// ---------------------------------------------------------------------------
// PROVEN round-6 CTC machinery, verbatim: 16 slots, 32 loads in flight,
// per-slot register-tied vmcnt(30); q generated 8 steps ahead of use.
// ---------------------------------------------------------------------------
#define CTC_REFILL(J, T)                                                      \
    {                                                                         \
        int tl_ = (T) <= last ? (T) : last;                                   \
        const char* rowp_ = pbase + (size_t)tl_ * 1000;                       \
        asm volatile("global_load_dwordx2 %0, %1, %2"                         \
                     : "=v"(lo[J]) : "v"(voff_lo), "s"(rowp_));               \
        asm volatile("global_load_dwordx2 %0, %1, %2"                         \
                     : "=v"(hi[J]) : "v"(voff_hi), "s"(rowp_));               \
    }

#define QGEN(Q, S, WCNT)                                                      \
    {                                                                         \
        asm volatile("s_waitcnt vmcnt(" #WCNT ")"                             \
                     : "+v"(lo[S]), "+v"(hi[S]));                             \
        qa[Q] = exp2fast(__builtin_fmaf(lo[S].x, LOG2E, bias0));              \
        qb[Q] = exp2fast(__builtin_fmaf(lo[S].y, LOG2E, bias1));              \
        qc[Q] = exp2fast(__builtin_fmaf(hi[S].x, LOG2E, bias2));              \
        qd[Q] = exp2fast(__builtin_fmaf(hi[S].y, LOG2E, bias3));              \
    }

#define STEP_Q(Q)                                                             \
    {                                                                         \
        float q0 = qa[Q], q1 = qb[Q], q2 = qc[Q], q3 = qd[Q];                 \
        float p7 = dpp_wave_shr1(a7); /* old a7 of lane-1; lane0 -> 0 */      \
        float s65 = a6 + a5, s43 = a4 + a3, s21 = a2 + a1, s0p = a0 + p7;     \
        a7 = (a7 + s65) * q3;  a6 = s65 * QB;                                 \
        a5 = (a5 + s43) * q2;  a4 = s43 * QB;                                 \
        a3 = (a3 + s21) * q1;  a2 = s21 * QB;                                 \
        a1 = (a1 + s0p) * q0;  a0 = s0p * QB;                                 \
    }

#define RENORM()                                                              \
    {                                                                         \
        float mx = fmaxf(fmaxf(fmaxf(a0, a1), fmaxf(a2, a3)),                 \
                         fmaxf(fmaxf(a4, a5), fmaxf(a6, a7)));                \
        mx = wave_red_max(mx); /* alphas >= 0, mx > 0 always */               \
        int e_ = (int)((__float_as_uint(mx) >> 23) & 255) - 127;              \
        float scale_ = __uint_as_float((unsigned)(127 - e_) << 23);           \
        a0 *= scale_; a1 *= scale_; a2 *= scale_; a3 *= scale_;               \
        a4 *= scale_; a5 *= scale_; a6 *= scale_; a7 *= scale_;               \
        Esum += (float)e_;                                                    \
    }

// Wave-1 step: same slot/wait skeleton as the proven CTC_STEP, but instead of
// the alpha update it accumulates the row's log-softmax denominator:
//   zacc += log2( e^{-1} + sum_{u<L} e^{logit_u} )   (log2 units)
// Masked lanes/dup-cols produce q == 0 exactly, so the wave sum counts each
// valid column once (identical semantics to the old zrow kernel's Z2).
#define ZSTEP(J, WCNT)                                                        \
    {                                                                         \
        asm volatile("s_waitcnt vmcnt(" #WCNT ")"                             \
                     : "+v"(lo[J]), "+v"(hi[J]));                             \
        float q0 = exp2fast(__builtin_fmaf(lo[J].x, LOG2E, bias0));           \
        float q1 = exp2fast(__builtin_fmaf(lo[J].y, LOG2E, bias1));           \
        float q2 = exp2fast(__builtin_fmaf(hi[J].x, LOG2E, bias2));           \
        float q3 = exp2fast(__builtin_fmaf(hi[J].y, LOG2E, bias3));           \
        float rsum = wave_red_sum((q0 + q1) + (q2 + q3));                     \
        zacc += log2fast(QB + rsum);                                          \
    }

// ---------------------------------------------------------------------------
// One block per batch, 128 threads = 2 waves.
//   wave 0: PROVEN round-6 alpha recursion (unchanged).
//   wave 1: zs-wave — streams the same rows, accumulates the per-row
//           log-softmax denominators; ~30 us of work hidden under wave 0's
//           ~83 us, on a different SIMD, reading L2-resident data.
// Handoff via LDS at a convergent __syncthreads (both waves reach it once).
// ---------------------------------------------------------------------------
__global__ void __launch_bounds__(128, 1) ctc_fused_kernel(
        const float* __restrict__ attn,
        const int* __restrict__ text_lens,
        const int* __restrict__ mel_lens,
        float* __restrict__ out) {
    int b = blockIdx.x;
    int lane = threadIdx.x & 63;
    int L = text_lens[b];
    int n_t = mel_lens[b];
    const char* pbase = (const char*)(attn + (size_t)b * Tn * Un);

    // per-lane safe byte offsets within a 1000B row (8B aligned, never OOB):
    // lane62 hi aliases lo (its cols 250/251 are always masked since L<=250),
    // lane63 reads col 0 (all its states masked).
    int voff_lo = lane * 16, voff_hi = lane * 16 + 8;
    if (lane == 62) { voff_lo = 992; voff_hi = 992; }
    if (lane == 63) { voff_lo = 0;   voff_hi = 0;   }
    int c0 = lane * 4;
    float bias0 = (c0 + 0 < L) ? 0.0f : -1000000.0f;
    float bias1 = (c0 + 1 < L) ? 0.0f : -1000000.0f;
    float bias2 = (c0 + 2 < L) ? 0.0f : -1000000.0f;
    float bias3 = (c0 + 3 < L) ? 0.0f : -1000000.0f;

    const float QB = 0.36787944117144233f;  // e^-1 (blank, unnormalized)
    float Esum = 0.0f;   // wave 0's renorm exponent (read by tid 0 in epilogue)
    v2f lo[16], hi[16];  // per-thread slots (each wave has its own copies)
    int last = n_t - 1;

    __shared__ float sal[512];
    __shared__ float salz;

    if (threadIdx.x < 64) {
        // ------------------ wave 0: PROVEN round-6 body ------------------
        float a0 = (lane == 0) ? 1.0f : 0.0f;
        float a1 = 0.0f, a2 = 0.0f, a3 = 0.0f, a4 = 0.0f, a5 = 0.0f,
              a6 = 0.0f, a7 = 0.0f;
        float qa[8], qb[8], qc[8], qd[8];

        // prologue: slots 0..15 <- rows 0..15 (32 loads in flight)
#pragma unroll
        for (int j = 0; j < 16; ++j) CTC_REFILL(j, j);
        QGEN(0, 0, 30); QGEN(1, 1, 28); QGEN(2, 2, 26); QGEN(3, 3, 24);
        QGEN(4, 4, 22); QGEN(5, 5, 20); QGEN(6, 6, 18); QGEN(7, 7, 16);
#pragma unroll
        for (int j = 0; j < 8; ++j) CTC_REFILL(j, 16 + j);

        int full = n_t & ~15;
        int t = 0;
        for (; t < full; t += 16) {
            STEP_Q(0); QGEN(0, 8, 30);  CTC_REFILL(8,  t + 24);
            STEP_Q(1); QGEN(1, 9, 30);  CTC_REFILL(9,  t + 25);
            STEP_Q(2); QGEN(2, 10, 30); CTC_REFILL(10, t + 26);
            STEP_Q(3); QGEN(3, 11, 30); CTC_REFILL(11, t + 27);
            STEP_Q(4); QGEN(4, 12, 30); CTC_REFILL(12, t + 28);
            STEP_Q(5); QGEN(5, 13, 30); CTC_REFILL(13, t + 29);
            STEP_Q(6); QGEN(6, 14, 30); CTC_REFILL(14, t + 30);
            STEP_Q(7); QGEN(7, 15, 30); CTC_REFILL(15, t + 31);
            RENORM();
            STEP_Q(0); QGEN(0, 0, 30);  CTC_REFILL(0, t + 32);
            STEP_Q(1); QGEN(1, 1, 30);  CTC_REFILL(1, t + 33);
            STEP_Q(2); QGEN(2, 2, 30);  CTC_REFILL(2, t + 34);
            STEP_Q(3); QGEN(3, 3, 30);  CTC_REFILL(3, t + 35);
            STEP_Q(4); QGEN(4, 4, 30);  CTC_REFILL(4, t + 36);
            STEP_Q(5); QGEN(5, 5, 30);  CTC_REFILL(5, t + 37);
            STEP_Q(6); QGEN(6, 6, 30);  CTC_REFILL(6, t + 38);
            STEP_Q(7); QGEN(7, 7, 30);  CTC_REFILL(7, t + 39);
            RENORM();
        }
        // tail (<= 15 steps). q[0..7] hold rows full..full+7; slots 8..14
        // hold rows full+8..full+14 (clamped).
        if (t + 0 < n_t) STEP_Q(0);
        if (t + 1 < n_t) STEP_Q(1);
        if (t + 2 < n_t) STEP_Q(2);
        if (t + 3 < n_t) STEP_Q(3);
        if (t + 4 < n_t) STEP_Q(4);
        if (t + 5 < n_t) STEP_Q(5);
        if (t + 6 < n_t) STEP_Q(6);
        if (t + 7 < n_t) STEP_Q(7);
        if (t + 8 < n_t)  { RENORM(); QGEN(0, 8, 0); STEP_Q(0); }  // cap run at 8
        if (t + 9 < n_t)  { QGEN(1, 9, 0);  STEP_Q(1); }
        if (t + 10 < n_t) { QGEN(2, 10, 0); STEP_Q(2); }
        if (t + 11 < n_t) { QGEN(3, 11, 0); STEP_Q(3); }
        if (t + 12 < n_t) { QGEN(4, 12, 0); STEP_Q(4); }
        if (t + 13 < n_t) { QGEN(5, 13, 0); STEP_Q(5); }
        if (t + 14 < n_t) { QGEN(6, 14, 0); STEP_Q(6); }
        asm volatile("s_waitcnt vmcnt(0)" ::: "memory");  // drain prefetches

        sal[lane * 8 + 0] = a0;
        sal[lane * 8 + 1] = a1;
        sal[lane * 8 + 2] = a2;
        sal[lane * 8 + 3] = a3;
        sal[lane * 8 + 4] = a4;
        sal[lane * 8 + 5] = a5;
        sal[lane * 8 + 6] = a6;
        sal[lane * 8 + 7] = a7;
    } else {
        // ------------------ wave 1: zs accumulation ------------------
        float zacc = 0.0f;  // sum over t < n_t of log2-denominators

        // prologue: slots 0..15 <- rows 0..15 (32 loads in flight)
#pragma unroll
        for (int j = 0; j < 16; ++j) CTC_REFILL(j, j);

        int full = n_t & ~15;
        int t = 0;
        for (; t < full; t += 16) {
            ZSTEP(0, 30);  CTC_REFILL(0, t + 16);
            ZSTEP(1, 30);  CTC_REFILL(1, t + 17);
            ZSTEP(2, 30);  CTC_REFILL(2, t + 18);
            ZSTEP(3, 30);  CTC_REFILL(3, t + 19);
            ZSTEP(4, 30);  CTC_REFILL(4, t + 20);
            ZSTEP(5, 30);  CTC_REFILL(5, t + 21);
            ZSTEP(6, 30);  CTC_REFILL(6, t + 22);
            ZSTEP(7, 30);  CTC_REFILL(7, t + 23);
            ZSTEP(8, 30);  CTC_REFILL(8, t + 24);
            ZSTEP(9, 30);  CTC_REFILL(9, t + 25);
            ZSTEP(10, 30); CTC_REFILL(10, t + 26);
            ZSTEP(11, 30); CTC_REFILL(11, t + 27);
            ZSTEP(12, 30); CTC_REFILL(12, t + 28);
            ZSTEP(13, 30); CTC_REFILL(13, t + 29);
            ZSTEP(14, 30); CTC_REFILL(14, t + 30);
            ZSTEP(15, 30); CTC_REFILL(15, t + 31);
        }
        // tail (<= 15 steps); slots j hold rows full+j (clamped)
        if (t + 0 < n_t) ZSTEP(0, 0);
        if (t + 1 < n_t) ZSTEP(1, 0);
        if (t + 2 < n_t) ZSTEP(2, 0);
        if (t + 3 < n_t) ZSTEP(3, 0);
        if (t + 4 < n_t) ZSTEP(4, 0);
        if (t + 5 < n_t) ZSTEP(5, 0);
        if (t + 6 < n_t) ZSTEP(6, 0);
        if (t + 7 < n_t) ZSTEP(7, 0);
        if (t + 8 < n_t) ZSTEP(8, 0);
        if (t + 9 < n_t) ZSTEP(9, 0);
        if (t + 10 < n_t) ZSTEP(10, 0);
        if (t + 11 < n_t) ZSTEP(11, 0);
        if (t + 12 < n_t) ZSTEP(12, 0);
        if (t + 13 < n_t) ZSTEP(13, 0);
        if (t + 14 < n_t) ZSTEP(14, 0);
        asm volatile("s_waitcnt vmcnt(0)" ::: "memory");  // drain prefetches

        if (threadIdx.x == 64) salz = zacc;  // zacc is wave-uniform (readlane)
    }

    __syncthreads();  // convergent: both waves arrive exactly once

    if (threadIdx.x == 0) {
        float zs = salz;
        float ssum = sal[2 * L] + sal[2 * L - 1];
        float fin = (log2fast(ssum) + Esum - zs) * LN2;
        float loss = (ssum <= 0.0f) ? 0.0f : (-fin / (float)L);
        atomicAdd(out, loss * (1.0f / (float)Bn));
    }
}

extern "C" void kernel_launch(void* const* d_in, const int* in_sizes, int n_in,
                              void* d_out, int out_size, void* d_ws, size_t ws_size,
                              hipStream_t stream) {
    const float* attn = (const float*)d_in[0];
    const int* text_lens = (const int*)d_in[1];
    const int* mel_lens = (const int*)d_in[2];
    float* out = (float*)d_out;

    // zero the scalar accumulator (stream-ordered; validated under capture)
    hipMemsetAsync(out, 0, sizeof(float), stream);
    ctc_fused_kernel<<<Bn, 128, 0, stream>>>(attn, text_lens, mel_lens, out);
}